// Round 8
// baseline (227.360 us; speedup 1.0000x reference)
//
#include <hip/hip_runtime.h>
#include <math.h>

#define N_ 32
#define D_ 512
#define S_ 1600
#define K_ 64

typedef __attribute__((ext_vector_type(8))) short short8;   // 8 bf16 = 16 B (A/B frag)
typedef __attribute__((ext_vector_type(4))) float f32x4;    // acc frag

// float -> bf16 (round to nearest even), bit pattern in short
static __device__ __forceinline__ short f2bf(float f) {
    unsigned u = __float_as_uint(f);
    u += 0x7fffu + ((u >> 16) & 1u);
    return (short)(u >> 16);
}

// ---------------------------------------------------------------------------
// kW: conv_weight [64][512] fp32 -> bf16
// ---------------------------------------------------------------------------
__global__ __launch_bounds__(256) void kW(const float* __restrict__ w,
                                          short* __restrict__ w16)
{
    int i4 = (blockIdx.x * 256 + threadIdx.x) * 4;
    float4 v = *(const float4*)&w[i4];
    short4 h = {f2bf(v.x), f2bf(v.y), f2bf(v.z), f2bf(v.w)};
    *(short4*)&w16[i4] = h;
}

// ---------------------------------------------------------------------------
// kX: streaming pass over x: x16[d][s] bf16 (full-line coalesced stores ONLY),
// fp32 ssq over d per pixel -> inv[n][s]. No in-loop LDS/barriers.
// grid: N * S/64 = 800 blocks x 256 thr; thread = (s = tid&63, dg = tid>>2).
// Each wave store = 64 lanes x 2B contiguous = one aligned 128-B line.
// ---------------------------------------------------------------------------
__global__ __launch_bounds__(256) void kX(const float* __restrict__ x,
                                          short* __restrict__ x16,
                                          float* __restrict__ inv)
{
    __shared__ float pssq[4][64];
    const int tid = threadIdx.x;
    const int n  = blockIdx.x / 25;
    const int s0 = (blockIdx.x % 25) * 64;
    const int sx = tid & 63;
    const int dg = tid >> 6;     // 0..3

    const float* xb = x + (size_t)n * D_ * S_ + s0 + sx;
    short* ob = x16 + (size_t)n * D_ * S_ + s0 + sx;

    float ss = 0.f;
#pragma unroll 8
    for (int r = dg; r < D_; r += 4) {
        float v = xb[(size_t)r * S_];
        ss += v * v;
        ob[(size_t)r * S_] = f2bf(v);
    }
    pssq[dg][sx] = ss;
    __syncthreads();
    if (tid < 64) {
        float t = pssq[0][tid] + pssq[1][tid] + pssq[2][tid] + pssq[3][tid];
        inv[(size_t)n * S_ + s0 + tid] = 1.0f / fmaxf(sqrtf(t), 1e-12f);
    }
}

// ---------------------------------------------------------------------------
// kA: MFMA GEMM logits[k][s] = sum_d w16[k][d] * x16[d][s] + fused softmax.
// Consumes bf16 x16 (L3-warm from kX): staging = raw b32 load -> 2 b16 LDS
// writes (no conversion VALU, NO global stores in the loop). inv precomputed.
// grid: 1600 blocks (n x s-tile 32) x 256 thr (4 waves).
// wave wv: k in [16wv,16wv+16), s = st*16+lk (st=0,1).
// D[row=4q+r <- k (A op)][col=lk <- s (B op)]  (round-4/6/7 verified).
// ---------------------------------------------------------------------------
__global__ __launch_bounds__(256) void kA(const short* __restrict__ x16,
                                          const short* __restrict__ w16,
                                          const float* __restrict__ inv,
                                          short* __restrict__ aprime,
                                          float* __restrict__ asum)
{
    __shared__ short T[32 * 68];        // [s][d] pitch 68 shorts (136 B rows)
    __shared__ float wred[2][4][32];

    const int tid = threadIdx.x;
    const int n  = blockIdx.x / 50;
    const int s0 = (blockIdx.x % 50) * 32;
    const int wv = tid >> 6;
    const int l  = tid & 63;
    const int lk = l & 15;
    const int q  = l >> 4;
    const int s2 = (tid & 15) * 2;   // staging: 2 s-cols per thread
    const int rr = tid >> 4;         // staging: d-row 0..15 (+16j)

    const short* xb = x16 + (size_t)n * D_ * S_ + s0;

    f32x4 acc[2];
    acc[0] = (f32x4){0.f, 0.f, 0.f, 0.f};
    acc[1] = (f32x4){0.f, 0.f, 0.f, 0.f};

    for (int dc = 0; dc < D_; dc += 64) {
        __syncthreads();
#pragma unroll
        for (int j = 0; j < 4; ++j) {
            const int row = rr + 16 * j;
            unsigned pv = *(const unsigned*)&xb[(size_t)(dc + row) * S_ + s2];
            T[s2 * 68 + row]       = (short)(pv & 0xffffu);
            T[(s2 + 1) * 68 + row] = (short)(pv >> 16);
        }
        __syncthreads();

#pragma unroll
        for (int kst = 0; kst < 2; ++kst) {
            short8 af = *(const short8*)&w16[(16 * wv + lk) * D_ + dc + kst * 32 + q * 8];
#pragma unroll
            for (int st = 0; st < 2; ++st) {
                const short* bp = &T[(st * 16 + lk) * 68 + kst * 32 + q * 8];
                short4 b0 = *(const short4*)bp;
                short4 b1 = *(const short4*)(bp + 4);
                short8 bf = {b0.x, b0.y, b0.z, b0.w, b1.x, b1.y, b1.z, b1.w};
                acc[st] = __builtin_amdgcn_mfma_f32_16x16x32_bf16(af, bf, acc[st], 0, 0, 0);
            }
        }
    }

    // epilogue: softmax over k (64 = 4r x 4q x 4wv) per s-column (st,lk)
    float lg[2][4], invv[2];
#pragma unroll
    for (int st = 0; st < 2; ++st) {
        invv[st] = inv[(size_t)n * S_ + s0 + st * 16 + lk];
#pragma unroll
        for (int r = 0; r < 4; ++r) lg[st][r] = acc[st][r] * invv[st];
    }
#pragma unroll
    for (int st = 0; st < 2; ++st) {
        float m = fmaxf(fmaxf(lg[st][0], lg[st][1]), fmaxf(lg[st][2], lg[st][3]));
        m = fmaxf(m, __shfl_xor(m, 16));
        m = fmaxf(m, __shfl_xor(m, 32));
        if (q == 0) wred[0][wv][st * 16 + lk] = m;
    }
    __syncthreads();
    float gm[2];
#pragma unroll
    for (int st = 0; st < 2; ++st) {
        float m = wred[0][0][st * 16 + lk];
        m = fmaxf(m, wred[0][1][st * 16 + lk]);
        m = fmaxf(m, wred[0][2][st * 16 + lk]);
        m = fmaxf(m, wred[0][3][st * 16 + lk]);
        gm[st] = m;
    }
    float e[2][4];
#pragma unroll
    for (int st = 0; st < 2; ++st) {
        float s = 0.f;
#pragma unroll
        for (int r = 0; r < 4; ++r) {
            e[st][r] = __expf(lg[st][r] - gm[st]);
            s += e[st][r];
        }
        s += __shfl_xor(s, 16);
        s += __shfl_xor(s, 32);
        if (q == 0) wred[1][wv][st * 16 + lk] = s;
    }
    __syncthreads();
    float rs[2];
#pragma unroll
    for (int st = 0; st < 2; ++st) {
        float s = wred[1][0][st * 16 + lk] + wred[1][1][st * 16 + lk]
                + wred[1][2][st * 16 + lk] + wred[1][3][st * 16 + lk];
        rs[st] = 1.0f / s;
    }

    short* apb = aprime + (size_t)n * K_ * S_ + s0;
#pragma unroll
    for (int r = 0; r < 4; ++r) {
        const int k = 16 * wv + 4 * q + r;
        float accp = 0.f;
#pragma unroll
        for (int st = 0; st < 2; ++st) {
            float p = e[st][r] * rs[st];
            apb[(size_t)k * S_ + st * 16 + lk] = f2bf(p * invv[st]);
            accp += p;
        }
        accp += __shfl_xor(accp, 1);
        accp += __shfl_xor(accp, 2);
        accp += __shfl_xor(accp, 4);
        accp += __shfl_xor(accp, 8);
        if (lk == 0) atomicAdd(&asum[n * K_ + k], accp);
    }
}

// ---------------------------------------------------------------------------
// kB: LDS-free MFMA GEMM. agg[k][d] partial over s-split:
//   agg[k][d] = sum_s aprime[k][s] * x16[d][s]   (both bf16, s-contiguous)
// grid: n(32) x dtile(4 of 128) x split(10 of 160s) = 1280 blocks x 256 thr.
// ---------------------------------------------------------------------------
__global__ __launch_bounds__(256) void kB(const short* __restrict__ x16,
                                          const short* __restrict__ aprime,
                                          float* __restrict__ aggp)
{
    const int bid = blockIdx.x;
    const int n  = bid / 40;
    const int dt = (bid % 40) / 10;
    const int sp = bid % 10;
    const int wv = threadIdx.x >> 6;
    const int l  = threadIdx.x & 63;
    const int lk = l & 15;
    const int q  = l >> 4;
    const int dbase = dt * 128 + wv * 32;

    const short* ap = aprime + (size_t)n * K_ * S_;
    const short* xb = x16 + (size_t)n * D_ * S_;

    f32x4 acc[4][2];
#pragma unroll
    for (int kt = 0; kt < 4; ++kt)
#pragma unroll
        for (int ds = 0; ds < 2; ++ds) acc[kt][ds] = (f32x4){0.f, 0.f, 0.f, 0.f};

#pragma unroll
    for (int kst = 0; kst < 5; ++kst) {
        const int s = sp * 160 + kst * 32 + q * 8;
        short8 af[4];
#pragma unroll
        for (int kt = 0; kt < 4; ++kt)
            af[kt] = *(const short8*)&ap[(size_t)(kt * 16 + lk) * S_ + s];
        short8 bf[2];
#pragma unroll
        for (int ds = 0; ds < 2; ++ds)
            bf[ds] = *(const short8*)&xb[(size_t)(dbase + ds * 16 + lk) * S_ + s];
#pragma unroll
        for (int kt = 0; kt < 4; ++kt)
#pragma unroll
            for (int ds = 0; ds < 2; ++ds)
                acc[kt][ds] = __builtin_amdgcn_mfma_f32_16x16x32_bf16(af[kt], bf[ds], acc[kt][ds], 0, 0, 0);
    }

    float* ab = aggp + ((size_t)sp * N_ + n) * K_ * D_;
#pragma unroll
    for (int kt = 0; kt < 4; ++kt)
#pragma unroll
        for (int ds = 0; ds < 2; ++ds)
#pragma unroll
            for (int r = 0; r < 4; ++r)
                ab[(size_t)(kt * 16 + 4 * q + r) * D_ + dbase + ds * 16 + lk] = acc[kt][ds][r];
}

// ---------------------------------------------------------------------------
// kC: vlad = (sum of 10 agg partials) - asum*centroid; intra-L2-norm over d;
// global norm = /sqrt(K) = /8 exactly. grid: 2048 blocks x 256 thr.
// ---------------------------------------------------------------------------
__global__ __launch_bounds__(256) void kC(const float* __restrict__ aggp,
                                          const float* __restrict__ asum,
                                          const float* __restrict__ cent,
                                          float* __restrict__ out)
{
    __shared__ float red[4];
    const int tid = threadIdx.x;
    const int nk = blockIdx.x;
    const int k = nk & 63;
    const float as = asum[nk];
    const float* cb = cent + (size_t)k * D_;

    float v0 = 0.f, v1 = 0.f;
#pragma unroll
    for (int p = 0; p < 10; ++p) {
        const float* ag = aggp + (size_t)p * N_ * K_ * D_ + (size_t)nk * D_;
        v0 += ag[tid];
        v1 += ag[tid + 256];
    }
    v0 -= as * cb[tid];
    v1 -= as * cb[tid + 256];
    float ssq = v0 * v0 + v1 * v1;

    ssq += __shfl_xor(ssq, 32);
    ssq += __shfl_xor(ssq, 16);
    ssq += __shfl_xor(ssq, 8);
    ssq += __shfl_xor(ssq, 4);
    ssq += __shfl_xor(ssq, 2);
    ssq += __shfl_xor(ssq, 1);
    if ((tid & 63) == 0) red[tid >> 6] = ssq;
    __syncthreads();
    const float total = red[0] + red[1] + red[2] + red[3];
    const float scale = 1.0f / (fmaxf(sqrtf(total), 1e-12f) * 8.0f);

    out[(size_t)nk * D_ + tid]       = v0 * scale;
    out[(size_t)nk * D_ + tid + 256] = v1 * scale;
}

// ---------------------------------------------------------------------------
extern "C" void kernel_launch(void* const* d_in, const int* in_sizes, int n_in,
                              void* d_out, int out_size, void* d_ws, size_t ws_size,
                              hipStream_t stream)
{
    const float* x    = (const float*)d_in[0];   // [32,512,40,40]
    const float* w    = (const float*)d_in[1];   // [64,512]
    const float* cent = (const float*)d_in[2];   // [64,512]
    float* out = (float*)d_out;                  // [32, 32768]

    // ws carve (~101 MB), fp32 first, all 16B-aligned
    float* aggp   = (float*)d_ws;                          // 10*N*K*D fp32
    float* asum   = aggp + (size_t)10 * N_ * K_ * D_;      // N*K fp32
    float* invb   = asum + (size_t)N_ * K_;                // N*S fp32
    short* aprime = (short*)(invb + (size_t)N_ * S_);      // N*K*S bf16
    short* w16    = aprime + (size_t)N_ * K_ * S_;         // K*D bf16
    short* x16    = w16 + (size_t)K_ * D_;                 // N*D*S bf16

    hipMemsetAsync(asum, 0, (size_t)N_ * K_ * sizeof(float), stream);

    kW<<<32, 256, 0, stream>>>(w, w16);
    kX<<<N_ * (S_ / 64), 256, 0, stream>>>(x, x16, invb);
    kA<<<N_ * (S_ / 32), 256, 0, stream>>>(x16, w16, invb, aprime, asum);
    kB<<<N_ * 4 * 10, 256, 0, stream>>>(x16, aprime, aggp);
    kC<<<N_ * K_, 256, 0, stream>>>(aggp, asum, cent, out);
}

// Round 9
// 224.691 us; speedup vs baseline: 1.0119x; 1.0119x over previous
//
#include <hip/hip_runtime.h>
#include <math.h>

#define N_ 32
#define D_ 512
#define S_ 1600
#define K_ 64
#define SP_ 10          // s-splits (160 s each, 5 chunks of 32)
#define PD_ 520         // T pitch in shorts (1040 B, 16B-aligned, bank-stride 4)
#define PA_ 40          // AL pitch in shorts (80 B, 16B-aligned)

typedef __attribute__((ext_vector_type(8))) short short8;   // 8 bf16 = 16 B frag
typedef __attribute__((ext_vector_type(4))) float f32x4;    // acc frag

static __device__ __forceinline__ short f2bf(float f) {
    unsigned u = __float_as_uint(f);
    u += 0x7fffu + ((u >> 16) & 1u);
    return (short)(u >> 16);
}

// ---------------------------------------------------------------------------
// kW: conv_weight [64][512] fp32 -> bf16
// ---------------------------------------------------------------------------
__global__ __launch_bounds__(256) void kW(const float* __restrict__ w,
                                          short* __restrict__ w16)
{
    int i4 = (blockIdx.x * 256 + threadIdx.x) * 4;
    float4 v = *(const float4*)&w[i4];
    short4 h = {f2bf(v.x), f2bf(v.y), f2bf(v.z), f2bf(v.w)};
    *(short4*)&w16[i4] = h;
}

// ---------------------------------------------------------------------------
// kX: streaming x -> x16[d][s] bf16 (full-line coalesced stores) + per-pixel
// fp32 ssq -> inv[n][s]. No in-loop barriers; loads pipeline freely.
// ---------------------------------------------------------------------------
__global__ __launch_bounds__(256) void kX(const float* __restrict__ x,
                                          short* __restrict__ x16,
                                          float* __restrict__ inv)
{
    __shared__ float pssq[4][64];
    const int tid = threadIdx.x;
    const int n  = blockIdx.x / 25;
    const int s0 = (blockIdx.x % 25) * 64;
    const int sx = tid & 63;
    const int dg = tid >> 6;

    const float* xb = x + (size_t)n * D_ * S_ + s0 + sx;
    short* ob = x16 + (size_t)n * D_ * S_ + s0 + sx;

    float ss = 0.f;
#pragma unroll 8
    for (int r = dg; r < D_; r += 4) {
        float v = xb[(size_t)r * S_];
        ss += v * v;
        ob[(size_t)r * S_] = f2bf(v);
    }
    pssq[dg][sx] = ss;
    __syncthreads();
    if (tid < 64) {
        float t = pssq[0][tid] + pssq[1][tid] + pssq[2][tid] + pssq[3][tid];
        inv[(size_t)n * S_ + s0 + tid] = 1.0f / fmaxf(sqrtf(t), 1e-12f);
    }
}

// ---------------------------------------------------------------------------
// kAB: fused logits+softmax+agg ("flash attention with Q=w", softmax over k
// is block-local so no online rescaling). Per chunk of 32 s:
//   1. stage x16[all d][chunk] -> T[s][d] (LDS transpose)
//   2. logits = w16 . T   (MFMA over d, 16 steps; per wave 16k x 32s)
//   3. fp32 softmax over all 64 k (cross-wave LDS reduce), p
//   4. AL[k][s] = bf16(p * inv)  (LDS)
//   5. agg[k][dslice] += AL . x16[d][chunk]  (MFMA over s, B straight from
//      global like old kB)
// asum accumulated in registers -> per-block partial store (NO atomics).
// grid: n(32) x sp(10 of 160 s) x dq(2 of 256 d) = 640 blocks x 256 thr.
// Fragment conventions identical to verified rounds 4-8:
//   A-frag m=lane&15, B-frag n=lane&15, k-dim offset q*8;
//   D[row=4q+r <- A operand][col=lk <- B operand].
// dq duplicates logits/softmax (cheap); only dq==0 writes asum partials.
// ---------------------------------------------------------------------------
__global__ __launch_bounds__(256) void kAB(const short* __restrict__ x16,
                                           const short* __restrict__ w16,
                                           const float* __restrict__ inv,
                                           float* __restrict__ aggp,
                                           float* __restrict__ asump)
{
    __shared__ short T[32 * PD_];       // [s][d] 33.3 KB
    __shared__ short AL[64 * PA_];      // [k][s] 5.1 KB
    __shared__ float wred[2][4][32];

    const int tid = threadIdx.x;
    const int bid = blockIdx.x;
    const int n  = bid / 20;
    const int rm = bid % 20;
    const int sp = rm >> 1;
    const int dq = rm & 1;
    const int wv = tid >> 6;
    const int l  = tid & 63;
    const int lk = l & 15;
    const int q  = l >> 4;
    const int sbase = sp * 160;
    const int dwave = dq * 256 + wv * 64;     // this wave's 64-d agg slice

    const short* xn = x16 + (size_t)n * D_ * S_;
    const int s2 = (tid & 15) * 2;            // staging: 2 s-cols
    const int r0 = tid >> 4;                  // staging: d-row base 0..15

    f32x4 agg[4][4];                          // [kt][ds]
#pragma unroll
    for (int kt = 0; kt < 4; ++kt)
#pragma unroll
        for (int ds = 0; ds < 4; ++ds) agg[kt][ds] = (f32x4){0.f, 0.f, 0.f, 0.f};
    float sreg[2][4] = {{0.f,0.f,0.f,0.f},{0.f,0.f,0.f,0.f}};

    for (int c = 0; c < 5; ++c) {
        const int sc = sbase + c * 32;
        __syncthreads();                      // protect T (and prior AL reads)
        // 1. stage: b32 load (2 s of one d-row) -> 2 b16 transposed LDS writes
#pragma unroll 8
        for (int j = 0; j < 32; ++j) {
            const int row = r0 + 16 * j;
            unsigned pv = *(const unsigned*)&xn[(size_t)row * S_ + sc + s2];
            T[s2 * PD_ + row]       = (short)(pv & 0xffffu);
            T[(s2 + 1) * PD_ + row] = (short)(pv >> 16);
        }
        __syncthreads();

        // 2. logits: wave wv -> k in [16wv,16wv+16), s = st*16+lk
        f32x4 lacc[2];
        lacc[0] = (f32x4){0.f, 0.f, 0.f, 0.f};
        lacc[1] = (f32x4){0.f, 0.f, 0.f, 0.f};
#pragma unroll
        for (int dstep = 0; dstep < 16; ++dstep) {
            short8 af = *(const short8*)&w16[(16 * wv + lk) * D_ + dstep * 32 + q * 8];
#pragma unroll
            for (int st = 0; st < 2; ++st) {
                short8 bfr = *(const short8*)&T[(st * 16 + lk) * PD_ + dstep * 32 + q * 8];
                lacc[st] = __builtin_amdgcn_mfma_f32_16x16x32_bf16(af, bfr, lacc[st], 0, 0, 0);
            }
        }

        // 3. softmax over k (fp32), scaled by inv
        float lg[2][4], invv[2];
#pragma unroll
        for (int st = 0; st < 2; ++st) {
            invv[st] = inv[(size_t)n * S_ + sc + st * 16 + lk];
#pragma unroll
            for (int r = 0; r < 4; ++r) lg[st][r] = lacc[st][r] * invv[st];
        }
#pragma unroll
        for (int st = 0; st < 2; ++st) {
            float m = fmaxf(fmaxf(lg[st][0], lg[st][1]), fmaxf(lg[st][2], lg[st][3]));
            m = fmaxf(m, __shfl_xor(m, 16));
            m = fmaxf(m, __shfl_xor(m, 32));
            if (q == 0) wred[0][wv][st * 16 + lk] = m;
        }
        __syncthreads();
        float gm[2];
#pragma unroll
        for (int st = 0; st < 2; ++st) {
            float m = wred[0][0][st * 16 + lk];
            m = fmaxf(m, wred[0][1][st * 16 + lk]);
            m = fmaxf(m, wred[0][2][st * 16 + lk]);
            m = fmaxf(m, wred[0][3][st * 16 + lk]);
            gm[st] = m;
        }
        float e[2][4];
#pragma unroll
        for (int st = 0; st < 2; ++st) {
            float s = 0.f;
#pragma unroll
            for (int r = 0; r < 4; ++r) {
                e[st][r] = __expf(lg[st][r] - gm[st]);
                s += e[st][r];
            }
            s += __shfl_xor(s, 16);
            s += __shfl_xor(s, 32);
            if (q == 0) wred[1][wv][st * 16 + lk] = s;
        }
        __syncthreads();
#pragma unroll
        for (int st = 0; st < 2; ++st) {
            float s = wred[1][0][st * 16 + lk] + wred[1][1][st * 16 + lk]
                    + wred[1][2][st * 16 + lk] + wred[1][3][st * 16 + lk];
            float rs = 1.0f / s;
            // 4. p -> asum reg + AL (bf16 p*inv)
#pragma unroll
            for (int r = 0; r < 4; ++r) {
                float p = e[st][r] * rs;
                sreg[st][r] += p;
                AL[(16 * wv + 4 * q + r) * PA_ + st * 16 + lk] = f2bf(p * invv[st]);
            }
        }
        __syncthreads();                      // AL ready

        // 5. agg += AL . x16  over this chunk's 32 s
        short8 aal[4], bfx[4];
#pragma unroll
        for (int kt = 0; kt < 4; ++kt)
            aal[kt] = *(const short8*)&AL[(kt * 16 + lk) * PA_ + q * 8];
#pragma unroll
        for (int ds = 0; ds < 4; ++ds)
            bfx[ds] = *(const short8*)&xn[(size_t)(dwave + ds * 16 + lk) * S_ + sc + q * 8];
#pragma unroll
        for (int kt = 0; kt < 4; ++kt)
#pragma unroll
            for (int ds = 0; ds < 4; ++ds)
                agg[kt][ds] = __builtin_amdgcn_mfma_f32_16x16x32_bf16(aal[kt], bfx[ds], agg[kt][ds], 0, 0, 0);
    }

    // store agg partial [sp][n][k][d]
    float* ab = aggp + ((size_t)sp * N_ + n) * K_ * D_;
#pragma unroll
    for (int kt = 0; kt < 4; ++kt)
#pragma unroll
        for (int ds = 0; ds < 4; ++ds)
#pragma unroll
            for (int r = 0; r < 4; ++r)
                ab[(size_t)(kt * 16 + 4 * q + r) * D_ + dwave + ds * 16 + lk] = agg[kt][ds][r];

    // asum partial (deterministic, no atomics): reduce over s (st in-lane, lk shfl)
    float t4[4];
#pragma unroll
    for (int r = 0; r < 4; ++r) {
        float t = sreg[0][r] + sreg[1][r];
        t += __shfl_xor(t, 1);
        t += __shfl_xor(t, 2);
        t += __shfl_xor(t, 4);
        t += __shfl_xor(t, 8);
        t4[r] = t;
    }
    if (lk == 0 && dq == 0) {
        float4 st4 = {t4[0], t4[1], t4[2], t4[3]};
        *(float4*)&asump[((size_t)sp * N_ + n) * K_ + 16 * wv + 4 * q] = st4;
    }
}

// ---------------------------------------------------------------------------
// kC: vlad = (sum of 10 agg partials) - (sum of 10 asum partials)*centroid;
// intra-L2-norm over d; global norm = /sqrt(K) = /8 exactly.
// grid: 2048 blocks x 256 thr.
// ---------------------------------------------------------------------------
__global__ __launch_bounds__(256) void kC(const float* __restrict__ aggp,
                                          const float* __restrict__ asump,
                                          const float* __restrict__ cent,
                                          float* __restrict__ out)
{
    __shared__ float red[4];
    const int tid = threadIdx.x;
    const int nk = blockIdx.x;
    const int n = nk >> 6;
    const int k = nk & 63;

    float as = 0.f;
#pragma unroll
    for (int p = 0; p < SP_; ++p)
        as += asump[((size_t)p * N_ + n) * K_ + k];   // wave-uniform loads

    const float* cb = cent + (size_t)k * D_;
    float v0 = 0.f, v1 = 0.f;
#pragma unroll
    for (int p = 0; p < SP_; ++p) {
        const float* ag = aggp + ((size_t)p * N_ + n) * K_ * D_ + (size_t)k * D_;
        v0 += ag[tid];
        v1 += ag[tid + 256];
    }
    v0 -= as * cb[tid];
    v1 -= as * cb[tid + 256];
    float ssq = v0 * v0 + v1 * v1;

    ssq += __shfl_xor(ssq, 32);
    ssq += __shfl_xor(ssq, 16);
    ssq += __shfl_xor(ssq, 8);
    ssq += __shfl_xor(ssq, 4);
    ssq += __shfl_xor(ssq, 2);
    ssq += __shfl_xor(ssq, 1);
    if ((tid & 63) == 0) red[tid >> 6] = ssq;
    __syncthreads();
    const float total = red[0] + red[1] + red[2] + red[3];
    const float scale = 1.0f / (fmaxf(sqrtf(total), 1e-12f) * 8.0f);

    out[(size_t)nk * D_ + tid]       = v0 * scale;
    out[(size_t)nk * D_ + tid + 256] = v1 * scale;
}

// ---------------------------------------------------------------------------
extern "C" void kernel_launch(void* const* d_in, const int* in_sizes, int n_in,
                              void* d_out, int out_size, void* d_ws, size_t ws_size,
                              hipStream_t stream)
{
    const float* x    = (const float*)d_in[0];   // [32,512,40,40]
    const float* w    = (const float*)d_in[1];   // [64,512]
    const float* cent = (const float*)d_in[2];   // [64,512]
    float* out = (float*)d_out;                  // [32, 32768]

    // ws carve (~93 MB), fp32 first, all 16B-aligned
    float* aggp  = (float*)d_ws;                           // SP*N*K*D fp32
    float* asump = aggp + (size_t)SP_ * N_ * K_ * D_;      // SP*N*K fp32
    float* invb  = asump + (size_t)SP_ * N_ * K_;          // N*S fp32
    short* w16   = (short*)(invb + (size_t)N_ * S_);       // K*D bf16
    short* x16   = w16 + (size_t)K_ * D_;                  // N*D*S bf16

    kW<<<32, 256, 0, stream>>>(w, w16);
    kX<<<N_ * (S_ / 64), 256, 0, stream>>>(x, x16, invb);
    kAB<<<N_ * SP_ * 2, 256, 0, stream>>>(x16, w16, invb, aggp, asump);
    kC<<<N_ * K_, 256, 0, stream>>>(aggp, asump, cent, out);
}